// Round 1
// baseline (832.714 us; speedup 1.0000x reference)
//
#include <hip/hip_runtime.h>
#include <math.h>

// ClassificationBackbone: conv/attn pipeline, fp32 throughout.
// Workspace requirement: 5,056,320 floats ≈ 20.3 MB.

#define DEVINL __device__ __forceinline__

DEVINL float selu_f(float x) {
  const float scale = 1.0507009873554805f;
  const float alpha = 1.6732632423543772f;
  return scale * (x > 0.f ? x : alpha * (__expf(x) - 1.f));
}

// ---------------- prep: h = concat([x^0.25/255^0.25, x], batch) ----------------
__global__ __launch_bounds__(256) void k_prep(const float* __restrict__ x,
                                              float* __restrict__ h, int n) {
  const float invScale = 0.250244727f;  // 255^-0.25
  for (int i = blockIdx.x * blockDim.x + threadIdx.x; i < n;
       i += gridDim.x * blockDim.x) {
    float v = x[i];
    h[i] = sqrtf(sqrtf(v)) * invScale;
    h[n + i] = v;
  }
}

// ---------------- direct conv3x3 (+bias)(+selu)(+avgpool2) ----------------
template <bool POOL, bool DO_SELU, bool DO_BIAS>
__global__ __launch_bounds__(256) void k_conv3x3(
    const float* __restrict__ in, const float* __restrict__ w,
    const float* __restrict__ bias, float* __restrict__ outA,
    float* __restrict__ outB, int splitB, int Bn, int Cin, int Cout, int IH,
    int IW) {
  int CH = IH - 2, CW = IW - 2;
  int OH = POOL ? (CH >> 1) : CH;
  int OW = POOL ? (CW >> 1) : CW;
  int total = Bn * Cout * OH * OW;
  for (int idx = blockIdx.x * blockDim.x + threadIdx.x; idx < total;
       idx += gridDim.x * blockDim.x) {
    int px = idx % OW;
    int t1 = idx / OW;
    int py = t1 % OH;
    int t2 = t1 / OH;
    int oc = t2 % Cout;
    int b = t2 / Cout;
    const float* wp = w + oc * Cin * 9;
    const float* ib = in + (long)b * Cin * IH * IW;
    float r;
    if (POOL) {
      int iy = py * 2, ix = px * 2;
      float a00 = 0.f, a01 = 0.f, a10 = 0.f, a11 = 0.f;
      for (int ci = 0; ci < Cin; ++ci) {
        const float* ip = ib + (ci * IH + iy) * IW + ix;
        float p[4][4];
#pragma unroll
        for (int rr = 0; rr < 4; ++rr)
#pragma unroll
          for (int cc = 0; cc < 4; ++cc) p[rr][cc] = ip[rr * IW + cc];
        const float* wc = wp + ci * 9;
#pragma unroll
        for (int ky = 0; ky < 3; ++ky)
#pragma unroll
          for (int kx = 0; kx < 3; ++kx) {
            float ww = wc[ky * 3 + kx];
            a00 = fmaf(ww, p[ky][kx], a00);
            a01 = fmaf(ww, p[ky][kx + 1], a01);
            a10 = fmaf(ww, p[ky + 1][kx], a10);
            a11 = fmaf(ww, p[ky + 1][kx + 1], a11);
          }
      }
      if (DO_BIAS) {
        float bb = bias[oc];
        a00 += bb; a01 += bb; a10 += bb; a11 += bb;
      }
      if (DO_SELU) {
        a00 = selu_f(a00); a01 = selu_f(a01);
        a10 = selu_f(a10); a11 = selu_f(a11);
      }
      r = 0.25f * (a00 + a01 + a10 + a11);
    } else {
      float a = 0.f;
      for (int ci = 0; ci < Cin; ++ci) {
        const float* ip = ib + (ci * IH + py) * IW + px;
        const float* wc = wp + ci * 9;
#pragma unroll
        for (int ky = 0; ky < 3; ++ky)
#pragma unroll
          for (int kx = 0; kx < 3; ++kx)
            a = fmaf(wc[ky * 3 + kx], ip[ky * IW + kx], a);
      }
      if (DO_BIAS) a += bias[oc];
      if (DO_SELU) a = selu_f(a);
      r = a;
    }
    if (outB != nullptr && b >= splitB)
      outB[(((b - splitB) * Cout + oc) * OH + py) * OW + px] = r;
    else
      outA[((b * Cout + oc) * OH + py) * OW + px] = r;
  }
}

// ---------------- q/k/v 1x1 projections ----------------
__global__ __launch_bounds__(256) void k_qkv(
    const float* __restrict__ x, const float* __restrict__ wq,
    const float* __restrict__ bq, const float* __restrict__ wk,
    const float* __restrict__ bk, const float* __restrict__ wv,
    const float* __restrict__ bv, float* __restrict__ q, float* __restrict__ k,
    float* __restrict__ v, int Bn, int C, int D, int N) {
  int J = 2 * D + C;
  int total = Bn * J * N;
  for (int idx = blockIdx.x * blockDim.x + threadIdx.x; idx < total;
       idx += gridDim.x * blockDim.x) {
    int n = idx % N;
    int t = idx / N;
    int j = t % J;
    int b = t / J;
    const float* w;
    float bb;
    float* dst;
    if (j < D) {
      w = wq + j * C; bb = bq[j]; dst = q + ((long)b * D + j) * N;
    } else if (j < 2 * D) {
      int co = j - D;
      w = wk + co * C; bb = bk[co]; dst = k + ((long)b * D + co) * N;
    } else {
      int co = j - 2 * D;
      w = wv + co * C; bb = bv[co]; dst = v + ((long)b * C + co) * N;
    }
    const float* xb = x + (long)b * C * N + n;
    float a = bb;
    for (int ci = 0; ci < C; ++ci) a = fmaf(w[ci], xb[ci * N], a);
    dst[n] = a;
  }
}

// ---------------- flash self-attention + residual ----------------
// 512 threads = 8 waves. row = tid&63 (one output row n per lane),
// seg = tid>>6 splits the m-dimension 8 ways; partials merged via LDS.
// Energies are tiny (weights ~N(0,0.0025)) -> softmax without max-subtraction
// is exact (shift-invariant) and overflow-free.
template <int C, int D>
__global__ __launch_bounds__(512) void k_attn(
    const float* __restrict__ x, const float* __restrict__ q,
    const float* __restrict__ kk, const float* __restrict__ vv,
    const float* __restrict__ gamma_p, float* __restrict__ out, int N,
    int nb) {
  constexpr int TS = 128;               // m-tile
  constexpr int Cp = (C + 3) & ~3;      // pad channels to float4
  constexpr int Dp = 8;                 // pad qk dim to 2 x float4
  constexpr int SMEMF = TS * Dp + TS * Cp + 512 + 8 * 512;
  __shared__ __align__(16) float smem[SMEMF];
  float* kl = smem;                 // [TS][Dp]  (m-major, transposed)
  float* vl = smem + TS * Dp;       // [TS][Cp]
  float* smbuf = vl + TS * Cp;      // [8][64] softmax denominators
  float* chunk = smbuf + 512;       // [8][512] channel-chunk merge

  int b = blockIdx.x / nb;
  int brow = (blockIdx.x % nb) * 64;
  int tid = threadIdx.x;
  int row = tid & 63;
  int seg = tid >> 6;
  int n = brow + row;
  bool valid = n < N;

  const float* qb = q + (long)b * D * N;
  const float* kb = kk + (long)b * D * N;
  const float* vb = vv + (long)b * C * N;
  const float* xb = x + (long)b * C * N;
  float* ob = out + (long)b * C * N;

  float qr[Dp];
#pragma unroll
  for (int d = 0; d < Dp; ++d) qr[d] = (d < D && valid) ? qb[d * N + n] : 0.f;

  float acc[Cp];
#pragma unroll
  for (int c = 0; c < Cp; ++c) acc[c] = 0.f;
  float sm = 0.f;

  for (int mt = 0; mt < N; mt += TS) {
    int mend = min(TS, N - mt);
    __syncthreads();
    for (int i = tid; i < TS * Dp; i += 512) {
      int j = i % TS;
      int c = i / TS;
      kl[j * Dp + c] = (c < D && j < mend) ? kb[c * N + mt + j] : 0.f;
    }
    for (int i = tid; i < TS * Cp; i += 512) {
      int j = i % TS;
      int c = i / TS;
      vl[j * Cp + c] = (c < C && j < mend) ? vb[c * N + mt + j] : 0.f;
    }
    __syncthreads();
    int m0 = seg * (TS / 8);
    int m1 = min(m0 + TS / 8, mend);
    for (int m = m0; m < m1; ++m) {
      const float4* kp = (const float4*)(kl + m * Dp);
      float4 ka = kp[0], kb4 = kp[1];
      float e = qr[0] * ka.x;
      e = fmaf(qr[1], ka.y, e);
      e = fmaf(qr[2], ka.z, e);
      e = fmaf(qr[3], ka.w, e);
      e = fmaf(qr[4], kb4.x, e);
      e = fmaf(qr[5], kb4.y, e);
      e = fmaf(qr[6], kb4.z, e);
      e = fmaf(qr[7], kb4.w, e);
      float p = __expf(e);
      sm += p;
      const float4* vp = (const float4*)(vl + m * Cp);
#pragma unroll
      for (int cc = 0; cc < Cp / 4; ++cc) {
        float4 vq = vp[cc];
        acc[4 * cc + 0] = fmaf(p, vq.x, acc[4 * cc + 0]);
        acc[4 * cc + 1] = fmaf(p, vq.y, acc[4 * cc + 1]);
        acc[4 * cc + 2] = fmaf(p, vq.z, acc[4 * cc + 2]);
        acc[4 * cc + 3] = fmaf(p, vq.w, acc[4 * cc + 3]);
      }
    }
  }

  // merge the 8 m-segments per row
  __syncthreads();
  smbuf[tid] = sm;
  __syncthreads();
  float invS = 0.f;
  float g = gamma_p[0];
  if (tid < 64) {
    float S = 0.f;
#pragma unroll
    for (int s = 0; s < 8; ++s) S += smbuf[s * 64 + row];
    invS = 1.f / S;
  }
#pragma unroll
  for (int c0 = 0; c0 < C; c0 += 8) {
    __syncthreads();
#pragma unroll
    for (int cc = 0; cc < 8; ++cc)
      if (c0 + cc < C) chunk[cc * 512 + tid] = acc[c0 + cc];
    __syncthreads();
    if (tid < 64 && valid) {
#pragma unroll
      for (int cc = 0; cc < 8; ++cc) {
        if (c0 + cc < C) {
          float a = 0.f;
#pragma unroll
          for (int s = 0; s < 8; ++s) a += chunk[cc * 512 + s * 64 + row];
          ob[(c0 + cc) * N + n] = fmaf(g, a * invS, xb[(c0 + cc) * N + n]);
        }
      }
    }
  }
}

// ---------------- batchnorm stats: mean + rsqrt(var+eps) per channel --------
__global__ __launch_bounds__(256) void k_bnstats(const float* __restrict__ x,
                                                 float* __restrict__ stats,
                                                 int Bn, int C, int HW,
                                                 float eps) {
  int c = blockIdx.x;
  int tid = threadIdx.x;
  int cnt = Bn * HW;
  float s = 0.f, s2 = 0.f;
  for (int i = tid; i < cnt; i += blockDim.x) {
    int b = i / HW, r = i % HW;
    float v = x[((long)b * C + c) * HW + r];
    s += v;
    s2 += v * v;
  }
#pragma unroll
  for (int off = 32; off > 0; off >>= 1) {
    s += __shfl_down(s, off);
    s2 += __shfl_down(s2, off);
  }
  __shared__ float as_[4], as2_[4];
  int wid = tid >> 6;
  if ((tid & 63) == 0) { as_[wid] = s; as2_[wid] = s2; }
  __syncthreads();
  if (tid == 0) {
    float S = 0.f, S2 = 0.f;
#pragma unroll
    for (int ww = 0; ww < 4; ++ww) { S += as_[ww]; S2 += as2_[ww]; }
    float mean = S / (float)cnt;
    float var = S2 / (float)cnt - mean * mean;
    stats[c] = mean;
    stats[C + c] = rsqrtf(var + eps);
  }
}

// ---------------- BN apply + selu (+pool) ----------------
template <bool POOL>
__global__ __launch_bounds__(256) void k_bn_selu(
    const float* __restrict__ x, const float* __restrict__ stats,
    const float* __restrict__ g, const float* __restrict__ beta,
    float* __restrict__ out, int Bn, int C, int IH, int IW) {
  int OH = POOL ? (IH >> 1) : IH;
  int OW = POOL ? (IW >> 1) : IW;
  int total = Bn * C * OH * OW;
  for (int idx = blockIdx.x * blockDim.x + threadIdx.x; idx < total;
       idx += gridDim.x * blockDim.x) {
    int px = idx % OW;
    int t = idx / OW;
    int py = t % OH;
    t /= OH;
    int c = t % C;
    int b = t / C;
    float mean = stats[c], istd = stats[C + c];
    float gg = g[c], bb = beta[c];
    const float* ip = x + ((long)b * C + c) * IH * IW;
    float r;
    if (POOL) {
      int iy = py * 2, ix = px * 2;
      float v00 = selu_f((ip[iy * IW + ix] - mean) * istd * gg + bb);
      float v01 = selu_f((ip[iy * IW + ix + 1] - mean) * istd * gg + bb);
      float v10 = selu_f((ip[(iy + 1) * IW + ix] - mean) * istd * gg + bb);
      float v11 = selu_f((ip[(iy + 1) * IW + ix + 1] - mean) * istd * gg + bb);
      r = 0.25f * (v00 + v01 + v10 + v11);
    } else {
      r = selu_f((ip[py * IW + px] - mean) * istd * gg + bb);
    }
    out[((b * C + c) * OH + py) * OW + px] = r;
  }
}

static inline int gs(int total) { return (total + 255) / 256; }

extern "C" void kernel_launch(void* const* d_in, const int* in_sizes, int n_in,
                              void* d_out, int out_size, void* d_ws,
                              size_t ws_size, hipStream_t stream) {
  const float* x      = (const float*)d_in[0];
  const float* enc_w1 = (const float*)d_in[1];
  const float* enc_b1 = (const float*)d_in[2];
  const float* enc_w2 = (const float*)d_in[3];
  const float* enc_b2 = (const float*)d_in[4];
  const float* a1_wq  = (const float*)d_in[5];
  const float* a1_bq  = (const float*)d_in[6];
  const float* a1_wk  = (const float*)d_in[7];
  const float* a1_bk  = (const float*)d_in[8];
  const float* a1_wv  = (const float*)d_in[9];
  const float* a1_bv  = (const float*)d_in[10];
  const float* a1_g   = (const float*)d_in[11];
  const float* c1_w   = (const float*)d_in[12];
  const float* c1_b   = (const float*)d_in[13];
  const float* a2_wq  = (const float*)d_in[14];
  const float* a2_bq  = (const float*)d_in[15];
  const float* a2_wk  = (const float*)d_in[16];
  const float* a2_bk  = (const float*)d_in[17];
  const float* a2_wv  = (const float*)d_in[18];
  const float* a2_bv  = (const float*)d_in[19];
  const float* a2_g   = (const float*)d_in[20];
  const float* c2_w   = (const float*)d_in[21];
  const float* c2_b   = (const float*)d_in[22];
  const float* c3_w   = (const float*)d_in[23];
  const float* c3_g   = (const float*)d_in[24];
  const float* c3_be  = (const float*)d_in[25];
  const float* c4_w   = (const float*)d_in[26];
  const float* c4_g   = (const float*)d_in[27];
  const float* c4_be  = (const float*)d_in[28];
  const float* a3_wq  = (const float*)d_in[29];
  const float* a3_bq  = (const float*)d_in[30];
  const float* a3_wk  = (const float*)d_in[31];
  const float* a3_bk  = (const float*)d_in[32];
  const float* a3_wv  = (const float*)d_in[33];
  const float* a3_bv  = (const float*)d_in[34];
  const float* a3_g   = (const float*)d_in[35];

  float* out = (float*)d_out;
  float* W = (float*)d_ws;

  // region A: 1,920,000 floats; region B: 3,136,320 floats (liveness-reused)
  float* A = W;
  float* Bb = W + 1920000;

  float* h    = A;                 // (16,3,200,200)
  float* h1   = Bb;                // (16,20,99,99)
  float* h2   = A;                 // (8,40,48,48)  b<8 only
  float* xenc = out + 5120;        // (8,40,48,48)  b>=8 written directly
  float* q1 = Bb;                  // (8,5,2304)
  float* k1 = Bb + 92160;
  float* v1 = Bb + 184320;         // (8,40,2304)
  float* at1 = Bb + 921600;        // (8,40,2304)
  float* c1o = A;                  // (8,50,46,46)
  float* q2 = Bb;                  // (8,6,2116)
  float* k2 = Bb + 101568;
  float* v2 = Bb + 203136;         // (8,50,2116)
  float* at2 = Bb + 1100000;       // (8,50,2116)
  float* c2o = A + 900000;         // (8,40,22,22)
  float* c3o = A;                  // (8,30,20,20)
  float* st3 = A + 100000;         // 60
  float* c3p = A + 110000;         // (8,30,10,10)
  float* c4o = A + 140000;         // (8,10,8,8) = 5120
  float* st4 = A + 146000;         // 20
  float* c4b = A + 147000;         // (8,10,8,8)
  float* q3  = A + 153000;         // (8,1,64)
  float* k3  = A + 153512;
  float* v3  = A + 154024;         // (8,10,64)

  const int NOSPLIT = 1 << 30;

  // 1. prep
  {
    int n = 8 * 3 * 200 * 200;
    k_prep<<<gs(n), 256, 0, stream>>>(x, h, n);
  }
  // 2. enc conv1 + selu + pool : (16,3,200,200)->(16,20,99,99)
  {
    int total = 16 * 20 * 99 * 99;
    k_conv3x3<true, true, true><<<gs(total), 256, 0, stream>>>(
        h, enc_w1, enc_b1, h1, nullptr, NOSPLIT, 16, 3, 20, 200, 200);
  }
  // 3. enc conv2 + selu + pool : (16,20,99,99)->(16,40,48,48); b>=8 -> x_enc
  {
    int total = 16 * 40 * 48 * 48;
    k_conv3x3<true, true, true><<<gs(total), 256, 0, stream>>>(
        h1, enc_w2, enc_b2, h2, xenc, 8, 16, 20, 40, 99, 99);
  }
  // 4. attn1 qkv
  {
    int total = 8 * (2 * 5 + 40) * 2304;
    k_qkv<<<gs(total), 256, 0, stream>>>(h2, a1_wq, a1_bq, a1_wk, a1_bk, a1_wv,
                                         a1_bv, q1, k1, v1, 8, 40, 5, 2304);
  }
  // 5. attn1
  {
    int nb = (2304 + 63) / 64;
    k_attn<40, 5><<<dim3(8 * nb), 512, 0, stream>>>(h2, q1, k1, v1, a1_g, at1,
                                                    2304, nb);
  }
  // 6. c1 conv + selu : (8,40,48,48)->(8,50,46,46)
  {
    int total = 8 * 50 * 46 * 46;
    k_conv3x3<false, true, true><<<gs(total), 256, 0, stream>>>(
        at1, c1_w, c1_b, c1o, nullptr, NOSPLIT, 8, 40, 50, 48, 48);
  }
  // 7. attn2 qkv
  {
    int total = 8 * (2 * 6 + 50) * 2116;
    k_qkv<<<gs(total), 256, 0, stream>>>(c1o, a2_wq, a2_bq, a2_wk, a2_bk, a2_wv,
                                         a2_bv, q2, k2, v2, 8, 50, 6, 2116);
  }
  // 8. attn2
  {
    int nb = (2116 + 63) / 64;
    k_attn<50, 6><<<dim3(8 * nb), 512, 0, stream>>>(c1o, q2, k2, v2, a2_g, at2,
                                                    2116, nb);
  }
  // 9. c2 conv + selu + pool : (8,50,46,46)->(8,40,22,22)
  {
    int total = 8 * 40 * 22 * 22;
    k_conv3x3<true, true, true><<<gs(total), 256, 0, stream>>>(
        at2, c2_w, c2_b, c2o, nullptr, NOSPLIT, 8, 50, 40, 46, 46);
  }
  // 10. c3 conv (no bias, no act) : (8,40,22,22)->(8,30,20,20)
  {
    int total = 8 * 30 * 20 * 20;
    k_conv3x3<false, false, false><<<gs(total), 256, 0, stream>>>(
        c2o, c3_w, nullptr, c3o, nullptr, NOSPLIT, 8, 40, 30, 22, 22);
  }
  // 11-12. BN(c3) + selu + pool -> (8,30,10,10)
  k_bnstats<<<30, 256, 0, stream>>>(c3o, st3, 8, 30, 400, 1e-5f);
  {
    int total = 8 * 30 * 10 * 10;
    k_bn_selu<true><<<gs(total), 256, 0, stream>>>(c3o, st3, c3_g, c3_be, c3p,
                                                   8, 30, 20, 20);
  }
  // 13. c4 conv : (8,30,10,10)->(8,10,8,8)
  {
    int total = 8 * 10 * 8 * 8;
    k_conv3x3<false, false, false><<<gs(total), 256, 0, stream>>>(
        c3p, c4_w, nullptr, c4o, nullptr, NOSPLIT, 8, 30, 10, 10, 10);
  }
  // 14-15. BN(c4) + selu
  k_bnstats<<<10, 256, 0, stream>>>(c4o, st4, 8, 10, 64, 1e-5f);
  {
    int total = 8 * 10 * 8 * 8;
    k_bn_selu<false><<<gs(total), 256, 0, stream>>>(c4o, st4, c4_g, c4_be, c4b,
                                                    8, 10, 8, 8);
  }
  // 16. attn3 qkv
  {
    int total = 8 * (2 * 1 + 10) * 64;
    k_qkv<<<gs(total), 256, 0, stream>>>(c4b, a3_wq, a3_bq, a3_wk, a3_bk, a3_wv,
                                         a3_bv, q3, k3, v3, 8, 10, 1, 64);
  }
  // 17. attn3 -> out[0..5120)
  {
    k_attn<10, 1><<<dim3(8), 512, 0, stream>>>(c4b, q3, k3, v3, a3_g, out, 64,
                                               1);
  }
}